// Round 18
// baseline (90.578 us; speedup 1.0000x reference)
//
#include <hip/hip_runtime.h>
#include <hip/hip_bf16.h>
#include <math.h>

#define DD 1024          // D (in == out features)
#define BT 8192          // B*N tokens
#define TWO_PI 6.28318530717958647692f

typedef float f32x4 __attribute__((ext_vector_type(4)));
typedef short bf16x8 __attribute__((ext_vector_type(8)));
typedef unsigned short u16x8 __attribute__((ext_vector_type(8)));
typedef unsigned short u16x4 __attribute__((ext_vector_type(4)));
typedef const __attribute__((address_space(1))) void g_void;
typedef __attribute__((address_space(3))) void l_void;

__device__ __forceinline__ unsigned short f2bf(float f) {
  unsigned int u = __float_as_uint(f);
  unsigned int r = (u + 0x7FFFu + ((u >> 16) & 1u)) >> 16;   // RNE
  return (unsigned short)r;
}

// ---------------------------------------------------------------------------
// build_G: G[k,m] = sum_o W[k,o] e^{+2pi i o m/D}. One block per k-row;
// coalesced row reads (sparsity is per-row), scan compaction, twiddle table.
// ---------------------------------------------------------------------------
__global__ __launch_bounds__(256) void build_G_kernel(
    const float* __restrict__ Wr, const float* __restrict__ Wi,
    float2* __restrict__ Gf) {
  __shared__ float2 tw[DD];
  __shared__ int    oidx[64];
  __shared__ float2 wval[64];
  __shared__ int    sc[256];
  const int k = blockIdx.x, tid = threadIdx.x;

  for (int j = tid; j < DD; j += 256) {
    float s, c;
    sincosf((TWO_PI / DD) * (float)j, &s, &c);
    tw[j] = make_float2(c, s);
  }
  int cnt = 0;
  float2 wl[4];
  int    ol[4];
#pragma unroll
  for (int q = 0; q < 4; q++) {
    int o = tid + q * 256;
    float wr = Wr[(size_t)k * DD + o];
    float wi = Wi[(size_t)k * DD + o];
    if (wr != 0.f || wi != 0.f) { wl[cnt] = make_float2(wr, wi); ol[cnt] = o; cnt++; }
  }
  sc[tid] = cnt;
  __syncthreads();
#pragma unroll
  for (int dstep = 1; dstep < 256; dstep <<= 1) {
    int v = (tid >= dstep) ? sc[tid - dstep] : 0;
    __syncthreads();
    sc[tid] += v;
    __syncthreads();
  }
  int p = sc[tid] - cnt;
  for (int q = 0; q < cnt; q++) { oidx[p + q] = ol[q]; wval[p + q] = wl[q]; }
  __syncthreads();
  const int nnz = sc[255];
  for (int m = tid; m < DD; m += 256) {
    float re = 0.f, im = 0.f;
    for (int j = 0; j < nnz; j++) {
      int    o  = oidx[j];
      float2 w  = wval[j];
      float2 cs = tw[(o * m) & (DD - 1)];     // e^{+i th} = (c, s)
      re += w.x * cs.x - w.y * cs.y;
      im += w.x * cs.y + w.y * cs.x;
    }
    Gf[(size_t)k * DD + m] = make_float2(re, im);
  }
}

// ---------------------------------------------------------------------------
// transpose_G: Gt[m][k] = bf16(Re Gf[k][m]); Gt[m][1024+k] = bf16(Im).
// ---------------------------------------------------------------------------
__global__ __launch_bounds__(256) void transpose_G_kernel(
    const float2* __restrict__ Gf, unsigned short* __restrict__ Gt) {
  __shared__ float2 tile[64][65];
  const int k0 = blockIdx.x * 64, m0 = blockIdx.y * 64;
  for (int q = threadIdx.x; q < 64 * 64; q += 256) {
    int r = q >> 6, c = q & 63;                 // r: k, c: m
    tile[r][c] = Gf[(size_t)(k0 + r) * DD + m0 + c];
  }
  __syncthreads();
  for (int q = threadIdx.x; q < 64 * 64; q += 256) {
    int r = q >> 6, c = q & 63;                 // r: m, c: k
    float2 v = tile[c][r];
    Gt[(size_t)(m0 + r) * 2048 + k0 + c]        = f2bf(v.x);
    Gt[(size_t)(m0 + r) * 2048 + 1024 + k0 + c] = f2bf(v.y);
  }
}

// ---------------------------------------------------------------------------
// build_M + convert_x fused launch (independent jobs, one dispatch):
// blocks [0,256): P_z[m][d] = sum_{K in z-chunk} Gt[m][K] * B(d,K)
//   (B generated in-register; A via global_load_lds; 128x128, BK=32,
//    split-K x4, kLen=512). Compute-bound.
// blocks [256,4352): Xb = bf16(x) — streams under the MFMA compute.
// NOTE (R14 lesson): no __threadfence/atomic handoff — device-scope fences
// force per-XCD L2 writeback on this arch (cost >> a launch gap).
// ---------------------------------------------------------------------------
__global__ __launch_bounds__(256) void build_M_convert_kernel(
    const unsigned short* __restrict__ Gt,   // (1024 x 2048) bf16, m-major
    float* __restrict__ P,
    const float* __restrict__ X, unsigned short* __restrict__ Xb) {
  __shared__ __align__(16) unsigned short Asm[128 * 32];
  __shared__ __align__(16) unsigned short Bsm[128 * 32];
  const int tid = threadIdx.x;

  if (blockIdx.x >= 256) {                 // ---- convert_x part ----
    size_t i = (size_t)(blockIdx.x - 256) * 256 + tid;   // chunk of 8
    const float4* p = (const float4*)(X + i * 8);
    float4 a = p[0], c = p[1];
    u16x8 v;
    v[0] = f2bf(a.x); v[1] = f2bf(a.y); v[2] = f2bf(a.z); v[3] = f2bf(a.w);
    v[4] = f2bf(c.x); v[5] = f2bf(c.y); v[6] = f2bf(c.z); v[7] = f2bf(c.w);
    *(u16x8*)(Xb + i * 8) = v;
    return;
  }

  // ---- build_M part: 256 = (d-tile 8) x (m-tile 8) x (z 4) ----
  const int wave = tid >> 6, lane = tid & 63;
  const int wr = wave >> 1, wc = wave & 1;
  const int col0 = (blockIdx.x & 7) * 128;         // d
  const int row0 = ((blockIdx.x >> 3) & 7) * 128;  // m
  const int bz   = blockIdx.x >> 6;                // k-chunk
  const int kBeg = bz * 512;

  f32x4 acc[4][4] = {};

  for (int k0 = kBeg; k0 < kBeg + 512; k0 += 32) {
    __syncthreads();
#pragma unroll
    for (int is = 0; is < 2; is++) {     // A = Gt rows (m-major)
      int e = is * 256 + tid;
      int r = e >> 2, c = (e & 3) * 8;
      const unsigned short* ga = Gt + (size_t)(row0 + r) * 2048 + k0 + c;
      __builtin_amdgcn_global_load_lds((g_void*)ga,
          (l_void*)(Asm + is * 2048 + wave * 512), 16, 0, 0);
    }
#pragma unroll
    for (int is = 0; is < 2; is++) {     // B = generated twiddles
      int e = is * 256 + tid;
      int r = e >> 2, c = (e & 3) * 8;
      int d = col0 + r;
      u16x8 v;
#pragma unroll
      for (int q = 0; q < 8; q++) {
        int K   = k0 + c + q;
        int idx = (K * d) & (DD - 1);
        float s, cc;
        __sincosf((TWO_PI / DD) * (float)idx, &s, &cc);
        v[q] = f2bf((K < DD) ? cc : s);
      }
      *(u16x8*)(Bsm + e * 8) = v;
    }
    __syncthreads();

    bf16x8 af[4], bfr[4];
#pragma unroll
    for (int i = 0; i < 4; i++) {
      int ra = wr * 64 + i * 16 + (lane & 15);
      af[i]  = *(const bf16x8*)&Asm[ra * 32 + (lane >> 4) * 8];
      int rb = wc * 64 + i * 16 + (lane & 15);
      bfr[i] = *(const bf16x8*)&Bsm[rb * 32 + (lane >> 4) * 8];
    }
#pragma unroll
    for (int i = 0; i < 4; i++)
#pragma unroll
      for (int j = 0; j < 4; j++)
        acc[i][j] = __builtin_amdgcn_mfma_f32_16x16x32_bf16(af[i], bfr[j], acc[i][j], 0, 0, 0);
  }

  const int crow0 = row0 + wr * 64;
  const int ccol0 = col0 + wc * 64;
  float* O = P + (size_t)bz * DD * DD;
#pragma unroll
  for (int i = 0; i < 4; i++)
#pragma unroll
    for (int j = 0; j < 4; j++) {
      int cc = ccol0 + j * 16 + (lane & 15);
#pragma unroll
      for (int v = 0; v < 4; v++) {
        int rr = crow0 + i * 16 + (lane >> 4) * 4 + v;
        O[(size_t)rr * DD + cc] = acc[i][j][v];
      }
    }
}

// ---------------------------------------------------------------------------
// reduce_M: Mb[i] = bf16( sum_z P_z[i] / D ),  x4 vectorized, 4 partials.
// ---------------------------------------------------------------------------
__global__ __launch_bounds__(256) void reduce_M_kernel(
    const float* __restrict__ P, unsigned short* __restrict__ Mb) {
  const size_t NE = (size_t)DD * DD;
  size_t i = ((size_t)blockIdx.x * 256 + threadIdx.x) * 4;
  float4 s = *(const float4*)(P + i);
#pragma unroll
  for (int z = 1; z < 4; z++) {
    float4 p = *(const float4*)(P + z * NE + i);
    s.x += p.x; s.y += p.y; s.z += p.z; s.w += p.w;
  }
  const float inv = 1.0f / (float)DD;
  u16x4 v;
  v[0] = f2bf(s.x * inv); v[1] = f2bf(s.y * inv);
  v[2] = f2bf(s.z * inv); v[3] = f2bf(s.w * inv);
  *(u16x4*)(Mb + i) = v;
}

// ---------------------------------------------------------------------------
// gemm_y: Y[t][m] = sum_d Xb[t][d]*Mb[m][d] + bias[m].  BM=128 x BN=64 tile,
// 4 waves (2x2, wave-tile 64x32), BK=32, gload_lds w16, 2-barrier loop.
// Grid 1024 (4 blocks/CU, 16 waves/CU — double R13's latency-hiding pool).
// XCD chunk swizzle: xcd = L&7 owns w in [xcd*128, +128) = 8 row-panels x 16
// col-panels -> per-XCD L2 footprint 2MB A + 2MB B (same 4MB that worked in
// R12; R5's BN=64 WITHOUT swizzle scattered A-panels over all XCDs).
// ---------------------------------------------------------------------------
__global__ __launch_bounds__(256) void gemm_y_kernel(
    const unsigned short* __restrict__ Xb,   // (8192 x 1024) bf16
    const unsigned short* __restrict__ Mb,   // (1024 x 1024) bf16
    const float* __restrict__ bias,
    float* __restrict__ Y) {
  __shared__ __align__(16) unsigned short Asm[128 * 32];
  __shared__ __align__(16) unsigned short Bsm[64 * 32];
  const int tid  = threadIdx.x;
  const int wave = tid >> 6, lane = tid & 63;
  const int wr = wave >> 1, wc = wave & 1;

  // chunked XCD swizzle over 1024 tiles: w row-major over (by 64, bx 16)
  const int L  = blockIdx.x;
  const int w  = (L & 7) * 128 + (L >> 3);
  const int row0 = (w >> 4) * 128;
  const int col0 = (w & 15) * 64;

  f32x4 acc[4][2] = {};

  for (int k0 = 0; k0 < DD; k0 += 32) {
    __syncthreads();
    // A: 128x32 (512 chunks of 8 -> 2 loads/thread)
#pragma unroll
    for (int is = 0; is < 2; is++) {
      int e = is * 256 + tid;
      int r = e >> 2, c = (e & 3) * 8;
      const unsigned short* ga = Xb + (size_t)(row0 + r) * DD + k0 + c;
      __builtin_amdgcn_global_load_lds((g_void*)ga,
          (l_void*)(Asm + is * 2048 + wave * 512), 16, 0, 0);
    }
    // B: 64x32 (256 chunks -> 1 load/thread)
    {
      int r = tid >> 2, c = (tid & 3) * 8;
      const unsigned short* gb = Mb + (size_t)(col0 + r) * DD + k0 + c;
      __builtin_amdgcn_global_load_lds((g_void*)gb,
          (l_void*)(Bsm + wave * 512), 16, 0, 0);
    }
    __syncthreads();

    bf16x8 af[4], bfr[2];
#pragma unroll
    for (int i = 0; i < 4; i++) {
      int ra = wr * 64 + i * 16 + (lane & 15);
      af[i]  = *(const bf16x8*)&Asm[ra * 32 + (lane >> 4) * 8];
    }
#pragma unroll
    for (int j = 0; j < 2; j++) {
      int rb = wc * 32 + j * 16 + (lane & 15);
      bfr[j] = *(const bf16x8*)&Bsm[rb * 32 + (lane >> 4) * 8];
    }
#pragma unroll
    for (int i = 0; i < 4; i++)
#pragma unroll
      for (int j = 0; j < 2; j++)
        acc[i][j] = __builtin_amdgcn_mfma_f32_16x16x32_bf16(af[i], bfr[j], acc[i][j], 0, 0, 0);
  }

  const int crow0 = row0 + wr * 64;
  const int ccol0 = col0 + wc * 32;
  float bv[2];
#pragma unroll
  for (int j = 0; j < 2; j++)
    bv[j] = bias[ccol0 + j * 16 + (lane & 15)];
#pragma unroll
  for (int i = 0; i < 4; i++)
#pragma unroll
    for (int j = 0; j < 2; j++) {
      int cc = ccol0 + j * 16 + (lane & 15);
#pragma unroll
      for (int v = 0; v < 4; v++) {
        int rr = crow0 + i * 16 + (lane >> 4) * 4 + v;
        Y[(size_t)rr * DD + cc] = acc[i][j][v] + bv[j];
      }
    }
}

// ---------------------------------------------------------------------------
extern "C" void kernel_launch(void* const* d_in, const int* in_sizes, int n_in,
                              void* d_out, int out_size, void* d_ws, size_t ws_size,
                              hipStream_t stream) {
  const float* x    = (const float*)d_in[0];
  const float* wrp  = (const float*)d_in[1];
  const float* wip  = (const float*)d_in[2];
  const float* bias = (const float*)d_in[3];
  float*       y    = (float*)d_out;

  char* ws = (char*)d_ws;
  const size_t MB = 1024 * 1024;
  float2*         Gf = (float2*)(ws + 0);                // 8 MB  [k][m]
  unsigned short* Gt = (unsigned short*)(ws + 8 * MB);   // 4 MB  [m][2048]
  unsigned short* Mb = (unsigned short*)(ws + 12 * MB);  // 2 MB  [m][d]
  float*          P  = (float*)(ws + 16 * MB);           // 16 MB (4 partials)
  unsigned short* Xb = (unsigned short*)(ws + 32 * MB);  // 16 MB

  build_G_kernel<<<DD, 256, 0, stream>>>(wrp, wip, Gf);
  transpose_G_kernel<<<dim3(16, 16), 256, 0, stream>>>(Gf, Gt);
  // P (256 MFMA blocks, split-K x4) + Xb = bf16(x) (4096 blocks)
  build_M_convert_kernel<<<4352, 256, 0, stream>>>(Gt, P, x, Xb);
  reduce_M_kernel<<<DD, 256, 0, stream>>>(P, Mb);
  // Y = Xb . Mb^T + bias   (128x64 tiles, 1024 blocks, XCD-chunk swizzle)
  gemm_y_kernel<<<1024, 256, 0, stream>>>(Xb, Mb, bias, y);
}

// Round 19
// 87.726 us; speedup vs baseline: 1.0325x; 1.0325x over previous
//
#include <hip/hip_runtime.h>
#include <hip/hip_bf16.h>
#include <math.h>

#define DD 1024          // D (in == out features)
#define BT 8192          // B*N tokens
#define TWO_PI 6.28318530717958647692f

typedef float f32x4 __attribute__((ext_vector_type(4)));
typedef short bf16x8 __attribute__((ext_vector_type(8)));
typedef unsigned short u16x8 __attribute__((ext_vector_type(8)));
typedef unsigned short u16x4 __attribute__((ext_vector_type(4)));
typedef const __attribute__((address_space(1))) void g_void;
typedef __attribute__((address_space(3))) void l_void;

__device__ __forceinline__ unsigned short f2bf(float f) {
  unsigned int u = __float_as_uint(f);
  unsigned int r = (u + 0x7FFFu + ((u >> 16) & 1u)) >> 16;   // RNE
  return (unsigned short)r;
}

// ---------------------------------------------------------------------------
// build_G: G[k,m] = sum_o W[k,o] e^{+2pi i o m/D}. One block per k-row;
// coalesced row reads (sparsity is per-row), scan compaction, twiddle table.
// Output packed bf16 pairs (re lo, im hi) — rounding here is bitwise
// identical to rounding in transpose_G (same RNE, same values), but halves
// the intermediate traffic (8 MB -> 4 MB).
// ---------------------------------------------------------------------------
__global__ __launch_bounds__(256) void build_G_kernel(
    const float* __restrict__ Wr, const float* __restrict__ Wi,
    unsigned int* __restrict__ Gb) {
  __shared__ float2 tw[DD];
  __shared__ int    oidx[64];
  __shared__ float2 wval[64];
  __shared__ int    sc[256];
  const int k = blockIdx.x, tid = threadIdx.x;

  for (int j = tid; j < DD; j += 256) {
    float s, c;
    sincosf((TWO_PI / DD) * (float)j, &s, &c);
    tw[j] = make_float2(c, s);
  }
  int cnt = 0;
  float2 wl[4];
  int    ol[4];
#pragma unroll
  for (int q = 0; q < 4; q++) {
    int o = tid + q * 256;
    float wr = Wr[(size_t)k * DD + o];
    float wi = Wi[(size_t)k * DD + o];
    if (wr != 0.f || wi != 0.f) { wl[cnt] = make_float2(wr, wi); ol[cnt] = o; cnt++; }
  }
  sc[tid] = cnt;
  __syncthreads();
#pragma unroll
  for (int dstep = 1; dstep < 256; dstep <<= 1) {
    int v = (tid >= dstep) ? sc[tid - dstep] : 0;
    __syncthreads();
    sc[tid] += v;
    __syncthreads();
  }
  int p = sc[tid] - cnt;
  for (int q = 0; q < cnt; q++) { oidx[p + q] = ol[q]; wval[p + q] = wl[q]; }
  __syncthreads();
  const int nnz = sc[255];
  for (int m = tid; m < DD; m += 256) {
    float re = 0.f, im = 0.f;
    for (int j = 0; j < nnz; j++) {
      int    o  = oidx[j];
      float2 w  = wval[j];
      float2 cs = tw[(o * m) & (DD - 1)];     // e^{+i th} = (c, s)
      re += w.x * cs.x - w.y * cs.y;
      im += w.x * cs.y + w.y * cs.x;
    }
    Gb[(size_t)k * DD + m] =
        (unsigned int)f2bf(re) | ((unsigned int)f2bf(im) << 16);
  }
}

// ---------------------------------------------------------------------------
// transpose_G: Gt[m][k] = lo16(Gb[k][m]); Gt[m][1024+k] = hi16(Gb[k][m]).
// ---------------------------------------------------------------------------
__global__ __launch_bounds__(256) void transpose_G_kernel(
    const unsigned int* __restrict__ Gb, unsigned short* __restrict__ Gt) {
  __shared__ unsigned int tile[64][65];
  const int k0 = blockIdx.x * 64, m0 = blockIdx.y * 64;
  for (int q = threadIdx.x; q < 64 * 64; q += 256) {
    int r = q >> 6, c = q & 63;                 // r: k, c: m
    tile[r][c] = Gb[(size_t)(k0 + r) * DD + m0 + c];
  }
  __syncthreads();
  for (int q = threadIdx.x; q < 64 * 64; q += 256) {
    int r = q >> 6, c = q & 63;                 // r: m, c: k
    unsigned int v = tile[c][r];
    Gt[(size_t)(m0 + r) * 2048 + k0 + c]        = (unsigned short)(v & 0xFFFFu);
    Gt[(size_t)(m0 + r) * 2048 + 1024 + k0 + c] = (unsigned short)(v >> 16);
  }
}

// ---------------------------------------------------------------------------
// build_M + convert_x fused launch (independent jobs, one dispatch):
// blocks [0,256): P_z[m][d] = sum_{K in z-chunk} Gt[m][K] * B(d,K)
//   (B generated in-register; A via global_load_lds; 128x128, BK=32,
//    split-K x4, kLen=512 — R16 showed x2 regresses). Compute-bound.
// blocks [256,4352): Xb = bf16(x) — streams under the MFMA compute.
// NOTE (R14 lesson): no __threadfence/atomic handoff — device-scope fences
// force per-XCD L2 writeback on this arch (cost >> a launch gap).
// ---------------------------------------------------------------------------
__global__ __launch_bounds__(256) void build_M_convert_kernel(
    const unsigned short* __restrict__ Gt,   // (1024 x 2048) bf16, m-major
    float* __restrict__ P,
    const float* __restrict__ X, unsigned short* __restrict__ Xb) {
  __shared__ __align__(16) unsigned short Asm[128 * 32];
  __shared__ __align__(16) unsigned short Bsm[128 * 32];
  const int tid = threadIdx.x;

  if (blockIdx.x >= 256) {                 // ---- convert_x part ----
    size_t i = (size_t)(blockIdx.x - 256) * 256 + tid;   // chunk of 8
    const float4* p = (const float4*)(X + i * 8);
    float4 a = p[0], c = p[1];
    u16x8 v;
    v[0] = f2bf(a.x); v[1] = f2bf(a.y); v[2] = f2bf(a.z); v[3] = f2bf(a.w);
    v[4] = f2bf(c.x); v[5] = f2bf(c.y); v[6] = f2bf(c.z); v[7] = f2bf(c.w);
    *(u16x8*)(Xb + i * 8) = v;
    return;
  }

  // ---- build_M part: 256 = (d-tile 8) x (m-tile 8) x (z 4) ----
  const int wave = tid >> 6, lane = tid & 63;
  const int wr = wave >> 1, wc = wave & 1;
  const int col0 = (blockIdx.x & 7) * 128;         // d
  const int row0 = ((blockIdx.x >> 3) & 7) * 128;  // m
  const int bz   = blockIdx.x >> 6;                // k-chunk
  const int kBeg = bz * 512;

  f32x4 acc[4][4] = {};

  for (int k0 = kBeg; k0 < kBeg + 512; k0 += 32) {
    __syncthreads();
#pragma unroll
    for (int is = 0; is < 2; is++) {     // A = Gt rows (m-major)
      int e = is * 256 + tid;
      int r = e >> 2, c = (e & 3) * 8;
      const unsigned short* ga = Gt + (size_t)(row0 + r) * 2048 + k0 + c;
      __builtin_amdgcn_global_load_lds((g_void*)ga,
          (l_void*)(Asm + is * 2048 + wave * 512), 16, 0, 0);
    }
#pragma unroll
    for (int is = 0; is < 2; is++) {     // B = generated twiddles
      int e = is * 256 + tid;
      int r = e >> 2, c = (e & 3) * 8;
      int d = col0 + r;
      u16x8 v;
#pragma unroll
      for (int q = 0; q < 8; q++) {
        int K   = k0 + c + q;
        int idx = (K * d) & (DD - 1);
        float s, cc;
        __sincosf((TWO_PI / DD) * (float)idx, &s, &cc);
        v[q] = f2bf((K < DD) ? cc : s);
      }
      *(u16x8*)(Bsm + e * 8) = v;
    }
    __syncthreads();

    bf16x8 af[4], bfr[4];
#pragma unroll
    for (int i = 0; i < 4; i++) {
      int ra = wr * 64 + i * 16 + (lane & 15);
      af[i]  = *(const bf16x8*)&Asm[ra * 32 + (lane >> 4) * 8];
      int rb = wc * 64 + i * 16 + (lane & 15);
      bfr[i] = *(const bf16x8*)&Bsm[rb * 32 + (lane >> 4) * 8];
    }
#pragma unroll
    for (int i = 0; i < 4; i++)
#pragma unroll
      for (int j = 0; j < 4; j++)
        acc[i][j] = __builtin_amdgcn_mfma_f32_16x16x32_bf16(af[i], bfr[j], acc[i][j], 0, 0, 0);
  }

  const int crow0 = row0 + wr * 64;
  const int ccol0 = col0 + wc * 64;
  float* O = P + (size_t)bz * DD * DD;
#pragma unroll
  for (int i = 0; i < 4; i++)
#pragma unroll
    for (int j = 0; j < 4; j++) {
      int cc = ccol0 + j * 16 + (lane & 15);
#pragma unroll
      for (int v = 0; v < 4; v++) {
        int rr = crow0 + i * 16 + (lane >> 4) * 4 + v;
        O[(size_t)rr * DD + cc] = acc[i][j][v];
      }
    }
}

// ---------------------------------------------------------------------------
// reduce_M: Mb[i] = bf16( sum_z P_z[i] / D ),  x4 vectorized, 4 partials.
// ---------------------------------------------------------------------------
__global__ __launch_bounds__(256) void reduce_M_kernel(
    const float* __restrict__ P, unsigned short* __restrict__ Mb) {
  const size_t NE = (size_t)DD * DD;
  size_t i = ((size_t)blockIdx.x * 256 + threadIdx.x) * 4;
  float4 s = *(const float4*)(P + i);
#pragma unroll
  for (int z = 1; z < 4; z++) {
    float4 p = *(const float4*)(P + z * NE + i);
    s.x += p.x; s.y += p.y; s.z += p.z; s.w += p.w;
  }
  const float inv = 1.0f / (float)DD;
  u16x4 v;
  v[0] = f2bf(s.x * inv); v[1] = f2bf(s.y * inv);
  v[2] = f2bf(s.z * inv); v[3] = f2bf(s.w * inv);
  *(u16x4*)(Mb + i) = v;
}

// ---------------------------------------------------------------------------
// gemm_y (R12/R13-proven best): 128x128 tile, 4 waves, BK=32, gload_lds w16,
// 2-barrier loop + chunked XCD swizzle (xcd = L&7 owns an 8x8 tile square).
// Plain Y stores. R18 closed the occupancy axis (128x64+swizzle regressed).
// ---------------------------------------------------------------------------
__global__ __launch_bounds__(256) void gemm_y_kernel(
    const unsigned short* __restrict__ Xb,   // (8192 x 1024) bf16
    const unsigned short* __restrict__ Mb,   // (1024 x 1024) bf16
    const float* __restrict__ bias,
    float* __restrict__ Y) {
  __shared__ __align__(16) unsigned short Asm[128 * 32];
  __shared__ __align__(16) unsigned short Bsm[128 * 32];
  const int tid  = threadIdx.x;
  const int wave = tid >> 6, lane = tid & 63;
  const int wr = wave >> 1, wc = wave & 1;

  const int L  = blockIdx.x;
  const int w  = (L & 7) * 64 + (L >> 3);
  const int row0 = (w >> 3) * 128;
  const int col0 = (w & 7) * 128;

  f32x4 acc[4][4] = {};

  for (int k0 = 0; k0 < DD; k0 += 32) {
    __syncthreads();
#pragma unroll
    for (int is = 0; is < 2; is++) {
      int e = is * 256 + tid;
      int r = e >> 2, c = (e & 3) * 8;
      const unsigned short* ga = Xb + (size_t)(row0 + r) * DD + k0 + c;
      const unsigned short* gb = Mb + (size_t)(col0 + r) * DD + k0 + c;
      __builtin_amdgcn_global_load_lds((g_void*)ga,
          (l_void*)(Asm + is * 2048 + wave * 512), 16, 0, 0);
      __builtin_amdgcn_global_load_lds((g_void*)gb,
          (l_void*)(Bsm + is * 2048 + wave * 512), 16, 0, 0);
    }
    __syncthreads();

    bf16x8 af[4], bfr[4];
#pragma unroll
    for (int i = 0; i < 4; i++) {
      int ra = wr * 64 + i * 16 + (lane & 15);
      af[i]  = *(const bf16x8*)&Asm[ra * 32 + (lane >> 4) * 8];
      int rb = wc * 64 + i * 16 + (lane & 15);
      bfr[i] = *(const bf16x8*)&Bsm[rb * 32 + (lane >> 4) * 8];
    }
#pragma unroll
    for (int i = 0; i < 4; i++)
#pragma unroll
      for (int j = 0; j < 4; j++)
        acc[i][j] = __builtin_amdgcn_mfma_f32_16x16x32_bf16(af[i], bfr[j], acc[i][j], 0, 0, 0);
  }

  const int crow0 = row0 + wr * 64;
  const int ccol0 = col0 + wc * 64;
  float bv[4];
#pragma unroll
  for (int j = 0; j < 4; j++)
    bv[j] = bias[ccol0 + j * 16 + (lane & 15)];
#pragma unroll
  for (int i = 0; i < 4; i++)
#pragma unroll
    for (int j = 0; j < 4; j++) {
      int cc = ccol0 + j * 16 + (lane & 15);
#pragma unroll
      for (int v = 0; v < 4; v++) {
        int rr = crow0 + i * 16 + (lane >> 4) * 4 + v;
        Y[(size_t)rr * DD + cc] = acc[i][j][v] + bv[j];
      }
    }
}

// ---------------------------------------------------------------------------
extern "C" void kernel_launch(void* const* d_in, const int* in_sizes, int n_in,
                              void* d_out, int out_size, void* d_ws, size_t ws_size,
                              hipStream_t stream) {
  const float* x    = (const float*)d_in[0];
  const float* wrp  = (const float*)d_in[1];
  const float* wip  = (const float*)d_in[2];
  const float* bias = (const float*)d_in[3];
  float*       y    = (float*)d_out;

  char* ws = (char*)d_ws;
  const size_t MB = 1024 * 1024;
  unsigned int*   Gb = (unsigned int*)(ws + 0);          // 4 MB  [k][m] bf16x2
  unsigned short* Gt = (unsigned short*)(ws + 8 * MB);   // 4 MB  [m][2048]
  unsigned short* Mb = (unsigned short*)(ws + 12 * MB);  // 2 MB  [m][d]
  float*          P  = (float*)(ws + 16 * MB);           // 16 MB (4 partials)
  unsigned short* Xb = (unsigned short*)(ws + 32 * MB);  // 16 MB

  build_G_kernel<<<DD, 256, 0, stream>>>(wrp, wip, Gb);
  transpose_G_kernel<<<dim3(16, 16), 256, 0, stream>>>(Gb, Gt);
  // P (256 MFMA blocks, split-K x4) + Xb = bf16(x) (4096 blocks)
  build_M_convert_kernel<<<4352, 256, 0, stream>>>(Gt, P, x, Xb);
  reduce_M_kernel<<<DD, 256, 0, stream>>>(P, Mb);
  // Y = Xb . Mb^T + bias   (XCD-chunk swizzled 1-D grid)
  gemm_y_kernel<<<512, 256, 0, stream>>>(Xb, Mb, bias, y);
}

// Round 20
// 86.246 us; speedup vs baseline: 1.0502x; 1.0172x over previous
//
#include <hip/hip_runtime.h>
#include <hip/hip_bf16.h>
#include <math.h>

#define DD 1024          // D (in == out features)
#define BT 8192          // B*N tokens
#define TWO_PI 6.28318530717958647692f

typedef float f32x4 __attribute__((ext_vector_type(4)));
typedef short bf16x8 __attribute__((ext_vector_type(8)));
typedef unsigned short u16x8 __attribute__((ext_vector_type(8)));
typedef unsigned short u16x4 __attribute__((ext_vector_type(4)));
typedef const __attribute__((address_space(1))) void g_void;
typedef __attribute__((address_space(3))) void l_void;

__device__ __forceinline__ unsigned short f2bf(float f) {
  unsigned int u = __float_as_uint(f);
  unsigned int r = (u + 0x7FFFu + ((u >> 16) & 1u)) >> 16;   // RNE
  return (unsigned short)r;
}

// ---------------------------------------------------------------------------
// build_G: G[k,m] = sum_o W[k,o] e^{+2pi i o m/D}. One block per k-row;
// coalesced row reads (sparsity is per-row), scan compaction, twiddle table.
// Output packed bf16 pairs (re lo, im hi).
// ---------------------------------------------------------------------------
__global__ __launch_bounds__(256) void build_G_kernel(
    const float* __restrict__ Wr, const float* __restrict__ Wi,
    unsigned int* __restrict__ Gb) {
  __shared__ float2 tw[DD];
  __shared__ int    oidx[64];
  __shared__ float2 wval[64];
  __shared__ int    sc[256];
  const int k = blockIdx.x, tid = threadIdx.x;

  for (int j = tid; j < DD; j += 256) {
    float s, c;
    sincosf((TWO_PI / DD) * (float)j, &s, &c);
    tw[j] = make_float2(c, s);
  }
  int cnt = 0;
  float2 wl[4];
  int    ol[4];
#pragma unroll
  for (int q = 0; q < 4; q++) {
    int o = tid + q * 256;
    float wr = Wr[(size_t)k * DD + o];
    float wi = Wi[(size_t)k * DD + o];
    if (wr != 0.f || wi != 0.f) { wl[cnt] = make_float2(wr, wi); ol[cnt] = o; cnt++; }
  }
  sc[tid] = cnt;
  __syncthreads();
#pragma unroll
  for (int dstep = 1; dstep < 256; dstep <<= 1) {
    int v = (tid >= dstep) ? sc[tid - dstep] : 0;
    __syncthreads();
    sc[tid] += v;
    __syncthreads();
  }
  int p = sc[tid] - cnt;
  for (int q = 0; q < cnt; q++) { oidx[p + q] = ol[q]; wval[p + q] = wl[q]; }
  __syncthreads();
  const int nnz = sc[255];
  for (int m = tid; m < DD; m += 256) {
    float re = 0.f, im = 0.f;
    for (int j = 0; j < nnz; j++) {
      int    o  = oidx[j];
      float2 w  = wval[j];
      float2 cs = tw[(o * m) & (DD - 1)];     // e^{+i th} = (c, s)
      re += w.x * cs.x - w.y * cs.y;
      im += w.x * cs.y + w.y * cs.x;
    }
    Gb[(size_t)k * DD + m] =
        (unsigned int)f2bf(re) | ((unsigned int)f2bf(im) << 16);
  }
}

// ---------------------------------------------------------------------------
// transpose_G: Gt[m][k] = lo16(Gb[k][m]); Gt[m][1024+k] = hi16(Gb[k][m]).
// ---------------------------------------------------------------------------
__global__ __launch_bounds__(256) void transpose_G_kernel(
    const unsigned int* __restrict__ Gb, unsigned short* __restrict__ Gt) {
  __shared__ unsigned int tile[64][65];
  const int k0 = blockIdx.x * 64, m0 = blockIdx.y * 64;
  for (int q = threadIdx.x; q < 64 * 64; q += 256) {
    int r = q >> 6, c = q & 63;                 // r: k, c: m
    tile[r][c] = Gb[(size_t)(k0 + r) * DD + m0 + c];
  }
  __syncthreads();
  for (int q = threadIdx.x; q < 64 * 64; q += 256) {
    int r = q >> 6, c = q & 63;                 // r: m, c: k
    unsigned int v = tile[c][r];
    Gt[(size_t)(m0 + r) * 2048 + k0 + c]        = (unsigned short)(v & 0xFFFFu);
    Gt[(size_t)(m0 + r) * 2048 + 1024 + k0 + c] = (unsigned short)(v >> 16);
  }
}

// ---------------------------------------------------------------------------
// build_M + convert_x fused launch (independent jobs, one dispatch):
// blocks [0,256): P_z[m][d] = sum_{K in z-chunk} Gt[m][K] * B(d,K).
//   B(d,K) = Re/Im of e^{2pi i dK/D}, generated by COMPLEX-ROTATION
//   RECURRENCE (setup: 6 sincosf/block; per K-step: 64 FMA instead of 32
//   trans-pipe ops — the trans pipe was pacing these blocks). Each thread's
//   8 B-values are consecutive K at fixed d -> chain-multiply by
//   s = e^{2pi i d/D}; base advances by s^32 per K-step. <=23 chained fp32
//   mults -> rel err ~2e-6 << bf16 ULP. K-range per block stays in one
//   cos/sin half (kLen=512, halves 1024-aligned) -> block-uniform selector.
// blocks [256,4352): Xb = bf16(x) — streams under the MFMA compute.
// NOTE (R14): no fences/atomics — device-scope fence = per-XCD L2 writeback.
// ---------------------------------------------------------------------------
__global__ __launch_bounds__(256) void build_M_convert_kernel(
    const unsigned short* __restrict__ Gt,   // (1024 x 2048) bf16, m-major
    float* __restrict__ P,
    const float* __restrict__ X, unsigned short* __restrict__ Xb) {
  __shared__ __align__(16) unsigned short Asm[128 * 32];
  __shared__ __align__(16) unsigned short Bsm[128 * 32];
  const int tid = threadIdx.x;

  if (blockIdx.x >= 256) {                 // ---- convert_x part ----
    size_t i = (size_t)(blockIdx.x - 256) * 256 + tid;   // chunk of 8
    const float4* p = (const float4*)(X + i * 8);
    float4 a = p[0], c = p[1];
    u16x8 v;
    v[0] = f2bf(a.x); v[1] = f2bf(a.y); v[2] = f2bf(a.z); v[3] = f2bf(a.w);
    v[4] = f2bf(c.x); v[5] = f2bf(c.y); v[6] = f2bf(c.z); v[7] = f2bf(c.w);
    *(u16x8*)(Xb + i * 8) = v;
    return;
  }

  // ---- build_M part: 256 = (d-tile 8) x (m-tile 8) x (z 4) ----
  const int wave = tid >> 6, lane = tid & 63;
  const int wr = wave >> 1, wc = wave & 1;
  const int col0 = (blockIdx.x & 7) * 128;         // d
  const int row0 = ((blockIdx.x >> 3) & 7) * 128;  // m
  const int bz   = blockIdx.x >> 6;                // k-chunk
  const int kBeg = bz * 512;
  const bool useSin = (kBeg >= DD);

  // rotation-recurrence setup (once per block)
  float2 base[2], stp[2], s32[2];
#pragma unroll
  for (int is = 0; is < 2; is++) {
    int e = is * 256 + tid;
    int r = e >> 2, c = (e & 3) * 8;
    int d = col0 + r;
    float sn, cs_;
    __sincosf((TWO_PI / DD) * (float)((d * (kBeg + c)) & (DD - 1)), &sn, &cs_);
    base[is] = make_float2(cs_, sn);
    __sincosf((TWO_PI / DD) * (float)(d & (DD - 1)), &sn, &cs_);
    stp[is] = make_float2(cs_, sn);
    __sincosf((TWO_PI / DD) * (float)((32 * d) & (DD - 1)), &sn, &cs_);
    s32[is] = make_float2(cs_, sn);
  }

  f32x4 acc[4][4] = {};

  for (int k0 = kBeg; k0 < kBeg + 512; k0 += 32) {
    __syncthreads();
#pragma unroll
    for (int is = 0; is < 2; is++) {     // A = Gt rows (m-major)
      int e = is * 256 + tid;
      int r = e >> 2, c = (e & 3) * 8;
      const unsigned short* ga = Gt + (size_t)(row0 + r) * 2048 + k0 + c;
      __builtin_amdgcn_global_load_lds((g_void*)ga,
          (l_void*)(Asm + is * 2048 + wave * 512), 16, 0, 0);
    }
#pragma unroll
    for (int is = 0; is < 2; is++) {     // B = rotated twiddles
      int e = is * 256 + tid;
      u16x8 v;
      float2 t = base[is];
#pragma unroll
      for (int q = 0; q < 8; q++) {
        v[q] = f2bf(useSin ? t.y : t.x);
        float tx = t.x * stp[is].x - t.y * stp[is].y;
        t.y      = t.x * stp[is].y + t.y * stp[is].x;
        t.x = tx;
      }
      *(u16x8*)(Bsm + e * 8) = v;
      float bx   = base[is].x * s32[is].x - base[is].y * s32[is].y;
      base[is].y = base[is].x * s32[is].y + base[is].y * s32[is].x;
      base[is].x = bx;
    }
    __syncthreads();

    bf16x8 af[4], bfr[4];
#pragma unroll
    for (int i = 0; i < 4; i++) {
      int ra = wr * 64 + i * 16 + (lane & 15);
      af[i]  = *(const bf16x8*)&Asm[ra * 32 + (lane >> 4) * 8];
      int rb = wc * 64 + i * 16 + (lane & 15);
      bfr[i] = *(const bf16x8*)&Bsm[rb * 32 + (lane >> 4) * 8];
    }
#pragma unroll
    for (int i = 0; i < 4; i++)
#pragma unroll
      for (int j = 0; j < 4; j++)
        acc[i][j] = __builtin_amdgcn_mfma_f32_16x16x32_bf16(af[i], bfr[j], acc[i][j], 0, 0, 0);
  }

  const int crow0 = row0 + wr * 64;
  const int ccol0 = col0 + wc * 64;
  float* O = P + (size_t)bz * DD * DD;
#pragma unroll
  for (int i = 0; i < 4; i++)
#pragma unroll
    for (int j = 0; j < 4; j++) {
      int cc = ccol0 + j * 16 + (lane & 15);
#pragma unroll
      for (int v = 0; v < 4; v++) {
        int rr = crow0 + i * 16 + (lane >> 4) * 4 + v;
        O[(size_t)rr * DD + cc] = acc[i][j][v];
      }
    }
}

// ---------------------------------------------------------------------------
// reduce_M: Mb[i] = bf16( sum_z P_z[i] / D ),  x4 vectorized, 4 partials.
// ---------------------------------------------------------------------------
__global__ __launch_bounds__(256) void reduce_M_kernel(
    const float* __restrict__ P, unsigned short* __restrict__ Mb) {
  const size_t NE = (size_t)DD * DD;
  size_t i = ((size_t)blockIdx.x * 256 + threadIdx.x) * 4;
  float4 s = *(const float4*)(P + i);
#pragma unroll
  for (int z = 1; z < 4; z++) {
    float4 p = *(const float4*)(P + z * NE + i);
    s.x += p.x; s.y += p.y; s.z += p.z; s.w += p.w;
  }
  const float inv = 1.0f / (float)DD;
  u16x4 v;
  v[0] = f2bf(s.x * inv); v[1] = f2bf(s.y * inv);
  v[2] = f2bf(s.z * inv); v[3] = f2bf(s.w * inv);
  *(u16x4*)(Mb + i) = v;
}

// ---------------------------------------------------------------------------
// gemm_y (R12/R13-proven best): 128x128 tile, 4 waves, BK=32, gload_lds w16,
// 2-barrier loop + chunked XCD swizzle (xcd = L&7 owns an 8x8 tile square).
// ---------------------------------------------------------------------------
__global__ __launch_bounds__(256) void gemm_y_kernel(
    const unsigned short* __restrict__ Xb,   // (8192 x 1024) bf16
    const unsigned short* __restrict__ Mb,   // (1024 x 1024) bf16
    const float* __restrict__ bias,
    float* __restrict__ Y) {
  __shared__ __align__(16) unsigned short Asm[128 * 32];
  __shared__ __align__(16) unsigned short Bsm[128 * 32];
  const int tid  = threadIdx.x;
  const int wave = tid >> 6, lane = tid & 63;
  const int wr = wave >> 1, wc = wave & 1;

  const int L  = blockIdx.x;
  const int w  = (L & 7) * 64 + (L >> 3);
  const int row0 = (w >> 3) * 128;
  const int col0 = (w & 7) * 128;

  f32x4 acc[4][4] = {};

  for (int k0 = 0; k0 < DD; k0 += 32) {
    __syncthreads();
#pragma unroll
    for (int is = 0; is < 2; is++) {
      int e = is * 256 + tid;
      int r = e >> 2, c = (e & 3) * 8;
      const unsigned short* ga = Xb + (size_t)(row0 + r) * DD + k0 + c;
      const unsigned short* gb = Mb + (size_t)(col0 + r) * DD + k0 + c;
      __builtin_amdgcn_global_load_lds((g_void*)ga,
          (l_void*)(Asm + is * 2048 + wave * 512), 16, 0, 0);
      __builtin_amdgcn_global_load_lds((g_void*)gb,
          (l_void*)(Bsm + is * 2048 + wave * 512), 16, 0, 0);
    }
    __syncthreads();

    bf16x8 af[4], bfr[4];
#pragma unroll
    for (int i = 0; i < 4; i++) {
      int ra = wr * 64 + i * 16 + (lane & 15);
      af[i]  = *(const bf16x8*)&Asm[ra * 32 + (lane >> 4) * 8];
      int rb = wc * 64 + i * 16 + (lane & 15);
      bfr[i] = *(const bf16x8*)&Bsm[rb * 32 + (lane >> 4) * 8];
    }
#pragma unroll
    for (int i = 0; i < 4; i++)
#pragma unroll
      for (int j = 0; j < 4; j++)
        acc[i][j] = __builtin_amdgcn_mfma_f32_16x16x32_bf16(af[i], bfr[j], acc[i][j], 0, 0, 0);
  }

  const int crow0 = row0 + wr * 64;
  const int ccol0 = col0 + wc * 64;
  float bv[4];
#pragma unroll
  for (int j = 0; j < 4; j++)
    bv[j] = bias[ccol0 + j * 16 + (lane & 15)];
#pragma unroll
  for (int i = 0; i < 4; i++)
#pragma unroll
    for (int j = 0; j < 4; j++) {
      int cc = ccol0 + j * 16 + (lane & 15);
#pragma unroll
      for (int v = 0; v < 4; v++) {
        int rr = crow0 + i * 16 + (lane >> 4) * 4 + v;
        Y[(size_t)rr * DD + cc] = acc[i][j][v] + bv[j];
      }
    }
}

// ---------------------------------------------------------------------------
extern "C" void kernel_launch(void* const* d_in, const int* in_sizes, int n_in,
                              void* d_out, int out_size, void* d_ws, size_t ws_size,
                              hipStream_t stream) {
  const float* x    = (const float*)d_in[0];
  const float* wrp  = (const float*)d_in[1];
  const float* wip  = (const float*)d_in[2];
  const float* bias = (const float*)d_in[3];
  float*       y    = (float*)d_out;

  char* ws = (char*)d_ws;
  const size_t MB = 1024 * 1024;
  unsigned int*   Gb = (unsigned int*)(ws + 0);          // 4 MB  [k][m] bf16x2
  unsigned short* Gt = (unsigned short*)(ws + 8 * MB);   // 4 MB  [m][2048]
  unsigned short* Mb = (unsigned short*)(ws + 12 * MB);  // 2 MB  [m][d]
  float*          P  = (float*)(ws + 16 * MB);           // 16 MB (4 partials)
  unsigned short* Xb = (unsigned short*)(ws + 32 * MB);  // 16 MB

  build_G_kernel<<<DD, 256, 0, stream>>>(wrp, wip, Gb);
  transpose_G_kernel<<<dim3(16, 16), 256, 0, stream>>>(Gb, Gt);
  // P (256 MFMA blocks, split-K x4) + Xb = bf16(x) (4096 blocks)
  build_M_convert_kernel<<<4352, 256, 0, stream>>>(Gt, P, x, Xb);
  reduce_M_kernel<<<DD, 256, 0, stream>>>(P, Mb);
  // Y = Xb . Mb^T + bias   (XCD-chunk swizzled 1-D grid)
  gemm_y_kernel<<<512, 256, 0, stream>>>(Xb, Mb, bias, y);
}

// Round 21
// 85.600 us; speedup vs baseline: 1.0582x; 1.0075x over previous
//
#include <hip/hip_runtime.h>
#include <hip/hip_bf16.h>
#include <math.h>

#define DD 1024          // D (in == out features)
#define BT 8192          // B*N tokens
#define TWO_PI 6.28318530717958647692f

typedef float f32x4 __attribute__((ext_vector_type(4)));
typedef short bf16x8 __attribute__((ext_vector_type(8)));
typedef unsigned short u16x8 __attribute__((ext_vector_type(8)));
typedef unsigned short u16x4 __attribute__((ext_vector_type(4)));
typedef const __attribute__((address_space(1))) void g_void;
typedef __attribute__((address_space(3))) void l_void;

__device__ __forceinline__ unsigned short f2bf(float f) {
  unsigned int u = __float_as_uint(f);
  unsigned int r = (u + 0x7FFFu + ((u >> 16) & 1u)) >> 16;   // RNE
  return (unsigned short)r;
}

// ---------------------------------------------------------------------------
// build_G: G[k,m] = sum_o W[k,o] e^{+2pi i o m/D}. One block per k-row;
// coalesced row reads (sparsity is per-row), scan compaction, twiddle table.
// Output packed bf16 pairs (re lo, im hi).
// ---------------------------------------------------------------------------
__global__ __launch_bounds__(256) void build_G_kernel(
    const float* __restrict__ Wr, const float* __restrict__ Wi,
    unsigned int* __restrict__ Gb) {
  __shared__ float2 tw[DD];
  __shared__ int    oidx[64];
  __shared__ float2 wval[64];
  __shared__ int    sc[256];
  const int k = blockIdx.x, tid = threadIdx.x;

  for (int j = tid; j < DD; j += 256) {
    float s, c;
    sincosf((TWO_PI / DD) * (float)j, &s, &c);
    tw[j] = make_float2(c, s);
  }
  int cnt = 0;
  float2 wl[4];
  int    ol[4];
#pragma unroll
  for (int q = 0; q < 4; q++) {
    int o = tid + q * 256;
    float wr = Wr[(size_t)k * DD + o];
    float wi = Wi[(size_t)k * DD + o];
    if (wr != 0.f || wi != 0.f) { wl[cnt] = make_float2(wr, wi); ol[cnt] = o; cnt++; }
  }
  sc[tid] = cnt;
  __syncthreads();
#pragma unroll
  for (int dstep = 1; dstep < 256; dstep <<= 1) {
    int v = (tid >= dstep) ? sc[tid - dstep] : 0;
    __syncthreads();
    sc[tid] += v;
    __syncthreads();
  }
  int p = sc[tid] - cnt;
  for (int q = 0; q < cnt; q++) { oidx[p + q] = ol[q]; wval[p + q] = wl[q]; }
  __syncthreads();
  const int nnz = sc[255];
  for (int m = tid; m < DD; m += 256) {
    float re = 0.f, im = 0.f;
    for (int j = 0; j < nnz; j++) {
      int    o  = oidx[j];
      float2 w  = wval[j];
      float2 cs = tw[(o * m) & (DD - 1)];     // e^{+i th} = (c, s)
      re += w.x * cs.x - w.y * cs.y;
      im += w.x * cs.y + w.y * cs.x;
    }
    Gb[(size_t)k * DD + m] =
        (unsigned int)f2bf(re) | ((unsigned int)f2bf(im) << 16);
  }
}

// ---------------------------------------------------------------------------
// transpose_G: Gt[m][k] = lo16(Gb[k][m]); Gt[m][1024+k] = hi16(Gb[k][m]).
// ---------------------------------------------------------------------------
__global__ __launch_bounds__(256) void transpose_G_kernel(
    const unsigned int* __restrict__ Gb, unsigned short* __restrict__ Gt) {
  __shared__ unsigned int tile[64][65];
  const int k0 = blockIdx.x * 64, m0 = blockIdx.y * 64;
  for (int q = threadIdx.x; q < 64 * 64; q += 256) {
    int r = q >> 6, c = q & 63;                 // r: k, c: m
    tile[r][c] = Gb[(size_t)(k0 + r) * DD + m0 + c];
  }
  __syncthreads();
  for (int q = threadIdx.x; q < 64 * 64; q += 256) {
    int r = q >> 6, c = q & 63;                 // r: m, c: k
    unsigned int v = tile[c][r];
    Gt[(size_t)(m0 + r) * 2048 + k0 + c]        = (unsigned short)(v & 0xFFFFu);
    Gt[(size_t)(m0 + r) * 2048 + 1024 + k0 + c] = (unsigned short)(v >> 16);
  }
}

// ---------------------------------------------------------------------------
// build_M + convert_x fused launch (independent jobs, one dispatch):
// blocks [0,256): P_z[m][d] = sum_{K in z-chunk} Gt[m][K] * B(d,K).
//   B(d,K) = Re/Im of e^{2pi i dK/D}, generated by complex-rotation
//   recurrence (setup: 6 sincosf/block; per K-step: 64 FMA instead of 32
//   trans-pipe ops). <=23 chained fp32 mults -> rel err ~2e-6 << bf16 ULP.
// blocks [256,4352): Xb = bf16(x) — streams under the MFMA compute.
// NOTE (R14): no fences/atomics — device-scope fence = per-XCD L2 writeback.
// ---------------------------------------------------------------------------
__global__ __launch_bounds__(256) void build_M_convert_kernel(
    const unsigned short* __restrict__ Gt,   // (1024 x 2048) bf16, m-major
    float* __restrict__ P,
    const float* __restrict__ X, unsigned short* __restrict__ Xb) {
  __shared__ __align__(16) unsigned short Asm[128 * 32];
  __shared__ __align__(16) unsigned short Bsm[128 * 32];
  const int tid = threadIdx.x;

  if (blockIdx.x >= 256) {                 // ---- convert_x part ----
    size_t i = (size_t)(blockIdx.x - 256) * 256 + tid;   // chunk of 8
    const float4* p = (const float4*)(X + i * 8);
    float4 a = p[0], c = p[1];
    u16x8 v;
    v[0] = f2bf(a.x); v[1] = f2bf(a.y); v[2] = f2bf(a.z); v[3] = f2bf(a.w);
    v[4] = f2bf(c.x); v[5] = f2bf(c.y); v[6] = f2bf(c.z); v[7] = f2bf(c.w);
    *(u16x8*)(Xb + i * 8) = v;
    return;
  }

  // ---- build_M part: 256 = (d-tile 8) x (m-tile 8) x (z 4) ----
  const int wave = tid >> 6, lane = tid & 63;
  const int wr = wave >> 1, wc = wave & 1;
  const int col0 = (blockIdx.x & 7) * 128;         // d
  const int row0 = ((blockIdx.x >> 3) & 7) * 128;  // m
  const int bz   = blockIdx.x >> 6;                // k-chunk
  const int kBeg = bz * 512;
  const bool useSin = (kBeg >= DD);

  // rotation-recurrence setup (once per block)
  float2 base[2], stp[2], s32[2];
#pragma unroll
  for (int is = 0; is < 2; is++) {
    int e = is * 256 + tid;
    int r = e >> 2, c = (e & 3) * 8;
    int d = col0 + r;
    float sn, cs_;
    __sincosf((TWO_PI / DD) * (float)((d * (kBeg + c)) & (DD - 1)), &sn, &cs_);
    base[is] = make_float2(cs_, sn);
    __sincosf((TWO_PI / DD) * (float)(d & (DD - 1)), &sn, &cs_);
    stp[is] = make_float2(cs_, sn);
    __sincosf((TWO_PI / DD) * (float)((32 * d) & (DD - 1)), &sn, &cs_);
    s32[is] = make_float2(cs_, sn);
  }

  f32x4 acc[4][4] = {};

  for (int k0 = kBeg; k0 < kBeg + 512; k0 += 32) {
    __syncthreads();
#pragma unroll
    for (int is = 0; is < 2; is++) {     // A = Gt rows (m-major)
      int e = is * 256 + tid;
      int r = e >> 2, c = (e & 3) * 8;
      const unsigned short* ga = Gt + (size_t)(row0 + r) * 2048 + k0 + c;
      __builtin_amdgcn_global_load_lds((g_void*)ga,
          (l_void*)(Asm + is * 2048 + wave * 512), 16, 0, 0);
    }
#pragma unroll
    for (int is = 0; is < 2; is++) {     // B = rotated twiddles
      int e = is * 256 + tid;
      u16x8 v;
      float2 t = base[is];
#pragma unroll
      for (int q = 0; q < 8; q++) {
        v[q] = f2bf(useSin ? t.y : t.x);
        float tx = t.x * stp[is].x - t.y * stp[is].y;
        t.y      = t.x * stp[is].y + t.y * stp[is].x;
        t.x = tx;
      }
      *(u16x8*)(Bsm + e * 8) = v;
      float bx   = base[is].x * s32[is].x - base[is].y * s32[is].y;
      base[is].y = base[is].x * s32[is].y + base[is].y * s32[is].x;
      base[is].x = bx;
    }
    __syncthreads();

    bf16x8 af[4], bfr[4];
#pragma unroll
    for (int i = 0; i < 4; i++) {
      int ra = wr * 64 + i * 16 + (lane & 15);
      af[i]  = *(const bf16x8*)&Asm[ra * 32 + (lane >> 4) * 8];
      int rb = wc * 64 + i * 16 + (lane & 15);
      bfr[i] = *(const bf16x8*)&Bsm[rb * 32 + (lane >> 4) * 8];
    }
#pragma unroll
    for (int i = 0; i < 4; i++)
#pragma unroll
      for (int j = 0; j < 4; j++)
        acc[i][j] = __builtin_amdgcn_mfma_f32_16x16x32_bf16(af[i], bfr[j], acc[i][j], 0, 0, 0);
  }

  const int crow0 = row0 + wr * 64;
  const int ccol0 = col0 + wc * 64;
  float* O = P + (size_t)bz * DD * DD;
#pragma unroll
  for (int i = 0; i < 4; i++)
#pragma unroll
    for (int j = 0; j < 4; j++) {
      int cc = ccol0 + j * 16 + (lane & 15);
#pragma unroll
      for (int v = 0; v < 4; v++) {
        int rr = crow0 + i * 16 + (lane >> 4) * 4 + v;
        O[(size_t)rr * DD + cc] = acc[i][j][v];
      }
    }
}

// ---------------------------------------------------------------------------
// reduce_M: Mb[i] = bf16( sum_z P_z[i] / D ),  x4 vectorized, 4 partials.
// ---------------------------------------------------------------------------
__global__ __launch_bounds__(256) void reduce_M_kernel(
    const float* __restrict__ P, unsigned short* __restrict__ Mb) {
  const size_t NE = (size_t)DD * DD;
  size_t i = ((size_t)blockIdx.x * 256 + threadIdx.x) * 4;
  float4 s = *(const float4*)(P + i);
#pragma unroll
  for (int z = 1; z < 4; z++) {
    float4 p = *(const float4*)(P + z * NE + i);
    s.x += p.x; s.y += p.y; s.z += p.z; s.w += p.w;
  }
  const float inv = 1.0f / (float)DD;
  u16x4 v;
  v[0] = f2bf(s.x * inv); v[1] = f2bf(s.y * inv);
  v[2] = f2bf(s.z * inv); v[3] = f2bf(s.w * inv);
  *(u16x4*)(Mb + i) = v;
}

// ---------------------------------------------------------------------------
// gemm_y (R12/R13-proven best): 128x128 tile, 4 waves, BK=32, gload_lds w16,
// 2-barrier loop + chunked XCD swizzle (xcd = L&7 owns an 8x8 tile square).
// ---------------------------------------------------------------------------
__global__ __launch_bounds__(256) void gemm_y_kernel(
    const unsigned short* __restrict__ Xb,   // (8192 x 1024) bf16
    const unsigned short* __restrict__ Mb,   // (1024 x 1024) bf16
    const float* __restrict__ bias,
    float* __restrict__ Y) {
  __shared__ __align__(16) unsigned short Asm[128 * 32];
  __shared__ __align__(16) unsigned short Bsm[128 * 32];
  const int tid  = threadIdx.x;
  const int wave = tid >> 6, lane = tid & 63;
  const int wr = wave >> 1, wc = wave & 1;

  const int L  = blockIdx.x;
  const int w  = (L & 7) * 64 + (L >> 3);
  const int row0 = (w >> 3) * 128;
  const int col0 = (w & 7) * 128;

  f32x4 acc[4][4] = {};

  for (int k0 = 0; k0 < DD; k0 += 32) {
    __syncthreads();
#pragma unroll
    for (int is = 0; is < 2; is++) {
      int e = is * 256 + tid;
      int r = e >> 2, c = (e & 3) * 8;
      const unsigned short* ga = Xb + (size_t)(row0 + r) * DD + k0 + c;
      const unsigned short* gb = Mb + (size_t)(col0 + r) * DD + k0 + c;
      __builtin_amdgcn_global_load_lds((g_void*)ga,
          (l_void*)(Asm + is * 2048 + wave * 512), 16, 0, 0);
      __builtin_amdgcn_global_load_lds((g_void*)gb,
          (l_void*)(Bsm + is * 2048 + wave * 512), 16, 0, 0);
    }
    __syncthreads();

    bf16x8 af[4], bfr[4];
#pragma unroll
    for (int i = 0; i < 4; i++) {
      int ra = wr * 64 + i * 16 + (lane & 15);
      af[i]  = *(const bf16x8*)&Asm[ra * 32 + (lane >> 4) * 8];
      int rb = wc * 64 + i * 16 + (lane & 15);
      bfr[i] = *(const bf16x8*)&Bsm[rb * 32 + (lane >> 4) * 8];
    }
#pragma unroll
    for (int i = 0; i < 4; i++)
#pragma unroll
      for (int j = 0; j < 4; j++)
        acc[i][j] = __builtin_amdgcn_mfma_f32_16x16x32_bf16(af[i], bfr[j], acc[i][j], 0, 0, 0);
  }

  const int crow0 = row0 + wr * 64;
  const int ccol0 = col0 + wc * 64;
  float bv[4];
#pragma unroll
  for (int j = 0; j < 4; j++)
    bv[j] = bias[ccol0 + j * 16 + (lane & 15)];
#pragma unroll
  for (int i = 0; i < 4; i++)
#pragma unroll
    for (int j = 0; j < 4; j++) {
      int cc = ccol0 + j * 16 + (lane & 15);
#pragma unroll
      for (int v = 0; v < 4; v++) {
        int rr = crow0 + i * 16 + (lane >> 4) * 4 + v;
        Y[(size_t)rr * DD + cc] = acc[i][j][v] + bv[j];
      }
    }
}

// ---------------------------------------------------------------------------
extern "C" void kernel_launch(void* const* d_in, const int* in_sizes, int n_in,
                              void* d_out, int out_size, void* d_ws, size_t ws_size,
                              hipStream_t stream) {
  const float* x    = (const float*)d_in[0];
  const float* wrp  = (const float*)d_in[1];
  const float* wip  = (const float*)d_in[2];
  const float* bias = (const float*)d_in[3];
  float*       y    = (float*)d_out;

  char* ws = (char*)d_ws;
  const size_t MB = 1024 * 1024;
  unsigned int*   Gb = (unsigned int*)(ws + 0);          // 4 MB  [k][m] bf16x2
  unsigned short* Gt = (unsigned short*)(ws + 8 * MB);   // 4 MB  [m][2048]
  unsigned short* Mb = (unsigned short*)(ws + 12 * MB);  // 2 MB  [m][d]
  float*          P  = (float*)(ws + 16 * MB);           // 16 MB (4 partials)
  unsigned short* Xb = (unsigned short*)(ws + 32 * MB);  // 16 MB

  build_G_kernel<<<DD, 256, 0, stream>>>(wrp, wip, Gb);
  transpose_G_kernel<<<dim3(16, 16), 256, 0, stream>>>(Gb, Gt);
  // P (256 MFMA blocks, split-K x4) + Xb = bf16(x) (4096 blocks)
  build_M_convert_kernel<<<4352, 256, 0, stream>>>(Gt, P, x, Xb);
  reduce_M_kernel<<<DD, 256, 0, stream>>>(P, Mb);
  // Y = Xb . Mb^T + bias   (XCD-chunk swizzled 1-D grid)
  gemm_y_kernel<<<512, 256, 0, stream>>>(Xb, Mb, bias, y);
}